// Round 8
// baseline (233.155 us; speedup 1.0000x reference)
//
#include <hip/hip_runtime.h>
#include <hip/hip_bf16.h>
#include <math.h>

// Problem constants: B=4, H=16, L=4096, D=64, S=128
constexpr int BB = 4;
constexpr int HH = 16;
constexpr int LL = 4096;
constexpr int DD = 64;
constexpr int SS = 128;
constexpr int NT = 8;      // tiles (of 16 rows) per wave
// block = 256 thr = 4 waves; rows/block = 4*16*NT = 512; grid = 512 (2/CU, all resident)

// R8: persistent waves, ONE barrier total. c split to 3 bf16 planes in LDS
// once per block (R6-exact bf16x3 numerics: hi*hi in its own fp32 acc, 7
// small segments in a second acc). A-fragments built in registers directly
// from global x (per-lane loads, 1-tile prefetch -> vmcnt hides HBM latency
// under MFMA). Per-wave argmax via shuffle butterfly; coalesced 1KB stores.
// No cross-wave traffic after staging => no phase serialization (R6/R7 bug).

typedef __attribute__((ext_vector_type(8))) short bf16x8;
typedef __attribute__((ext_vector_type(4))) float f32x4;

__device__ __forceinline__ void split3reg(f32x4 v0, f32x4 v1,
                                          bf16x8& H8, bf16x8& M8, bf16x8& L8) {
    float v[8];
    *(f32x4*)&v[0] = v0;
    *(f32x4*)&v[4] = v1;
    short H[8], M[8], L[8];
    #pragma unroll
    for (int e = 0; e < 8; ++e) {
        const float xv = v[e];
        const unsigned u0 = __float_as_uint(xv);
        const float hf = __uint_as_float(u0 & 0xFFFF0000u);
        const float r1 = xv - hf;                       // exact
        const unsigned u1 = __float_as_uint(r1);
        const float mf = __uint_as_float(u1 & 0xFFFF0000u);
        const float r2 = r1 - mf;                       // exact, <=8 sig bits
        const unsigned u2 = __float_as_uint(r2);
        H[e] = (short)(u0 >> 16);
        M[e] = (short)(u1 >> 16);
        L[e] = (short)(u2 >> 16);                       // exact bf16
    }
    H8 = *(bf16x8*)H; M8 = *(bf16x8*)M; L8 = *(bf16x8*)L;
}

__global__ __launch_bounds__(256, 2) void quantizer_kernel(
    const float* __restrict__ x,   // [B,H,L,D]
    const float* __restrict__ c,   // [H,S,D]
    float* __restrict__ out,       // [B,H,L,S] one-hot
    float* __restrict__ out_c)     // [H,S,D] copy of c
{
    // B planes: 3 x [128 codes][80 shorts] (stride 160B: 16B-aligned b128)
    alignas(16) __shared__ short smem[3 * 128 * 80 + 128];
    short* __restrict__ sBh = smem;
    short* __restrict__ sBm = smem + 10240;
    short* __restrict__ sBl = smem + 20480;
    int*   __restrict__ swx = (int*)(smem + 30720);   // per-wave amax scratch

    const int tid = threadIdx.x;
    const int blk = blockIdx.x;
    const long long r0 = (long long)blk * 512;
    const int h = (blk >> 3) & (HH - 1);              // 512 | 4096
    const float* __restrict__ chead = c + (size_t)h * SS * DD;

    // ---- stage + split codebook: 1024 octet-tasks, 4 per thread ----
    #pragma unroll
    for (int i = 0; i < 4; ++i) {
        const int t = tid + i * 256;
        const int code = t >> 3, oct = t & 7;
        const f32x4* cp = (const f32x4*)(chead + code * DD + oct * 8);
        bf16x8 H, M, L;
        split3reg(cp[0], cp[1], H, M, L);
        *(bf16x8*)&sBh[code * 80 + oct * 8] = H;
        *(bf16x8*)&sBm[code * 80 + oct * 8] = M;
        *(bf16x8*)&sBl[code * 80 + oct * 8] = L;
    }
    __syncthreads();   // the ONLY barrier

    const int lane = tid & 63;
    const int w = tid >> 6;        // wave id 0..3
    const int lm = lane & 15;      // m-row / n-code within 16x16 tile
    const int q  = lane >> 4;      // k-group (k = q*8+j) / D-row quad

    // per-lane x loads for A fragments: row rw0+lm, k halves [q*8, q*8+8)
    auto loadraw = [&](long long rw0, f32x4& a0, f32x4& a1, f32x4& b0, f32x4& b1) {
        const float* p = x + (rw0 + lm) * (long long)DD;
        a0 = *(const f32x4*)(p + q * 8);
        a1 = *(const f32x4*)(p + q * 8 + 4);
        b0 = *(const f32x4*)(p + 32 + q * 8);
        b1 = *(const f32x4*)(p + 32 + q * 8 + 4);
    };

    f32x4 ra0, ra1, rb0, rb1;                  // current tile raw x
    f32x4 na0 = {}, na1 = {}, nb0 = {}, nb1 = {};
    loadraw(r0 + w * 16, ra0, ra1, rb0, rb1);

    #pragma unroll 1
    for (int t = 0; t < NT; ++t) {
        const long long rw0 = r0 + t * 64 + w * 16;
        if (t + 1 < NT) loadraw(rw0 + 64, na0, na1, nb0, nb1);   // prefetch

        bf16x8 Ah0, Am0, Al0, Ah1, Am1, Al1;
        split3reg(ra0, ra1, Ah0, Am0, Al0);
        split3reg(rb0, rb1, Ah1, Am1, Al1);

        f32x4 accB[8] = {};   // hi*hi
        f32x4 accS[8] = {};   // 7 small segments
        #pragma unroll
        for (int b = 0; b < 8; ++b) {
            const int n = b * 16 + lm;
            const bf16x8 Bh0 = *(const bf16x8*)&sBh[n * 80 + q * 8];
            const bf16x8 Bm0 = *(const bf16x8*)&sBm[n * 80 + q * 8];
            const bf16x8 Bl0 = *(const bf16x8*)&sBl[n * 80 + q * 8];
            const bf16x8 Bh1 = *(const bf16x8*)&sBh[n * 80 + 32 + q * 8];
            const bf16x8 Bm1 = *(const bf16x8*)&sBm[n * 80 + 32 + q * 8];
            const bf16x8 Bl1 = *(const bf16x8*)&sBl[n * 80 + 32 + q * 8];
            accB[b] = __builtin_amdgcn_mfma_f32_16x16x32_bf16(Ah0, Bh0, accB[b], 0, 0, 0);
            accB[b] = __builtin_amdgcn_mfma_f32_16x16x32_bf16(Ah1, Bh1, accB[b], 0, 0, 0);
            accS[b] = __builtin_amdgcn_mfma_f32_16x16x32_bf16(Ah0, Bm0, accS[b], 0, 0, 0);
            accS[b] = __builtin_amdgcn_mfma_f32_16x16x32_bf16(Am0, Bh0, accS[b], 0, 0, 0);
            accS[b] = __builtin_amdgcn_mfma_f32_16x16x32_bf16(Am0, Bm0, accS[b], 0, 0, 0);
            accS[b] = __builtin_amdgcn_mfma_f32_16x16x32_bf16(Ah0, Bl0, accS[b], 0, 0, 0);
            accS[b] = __builtin_amdgcn_mfma_f32_16x16x32_bf16(Al0, Bh0, accS[b], 0, 0, 0);
            accS[b] = __builtin_amdgcn_mfma_f32_16x16x32_bf16(Am0, Bl0, accS[b], 0, 0, 0);
            accS[b] = __builtin_amdgcn_mfma_f32_16x16x32_bf16(Al0, Bm0, accS[b], 0, 0, 0);
            accS[b] = __builtin_amdgcn_mfma_f32_16x16x32_bf16(Ah1, Bm1, accS[b], 0, 0, 0);
            accS[b] = __builtin_amdgcn_mfma_f32_16x16x32_bf16(Am1, Bh1, accS[b], 0, 0, 0);
            accS[b] = __builtin_amdgcn_mfma_f32_16x16x32_bf16(Am1, Bm1, accS[b], 0, 0, 0);
            accS[b] = __builtin_amdgcn_mfma_f32_16x16x32_bf16(Ah1, Bl1, accS[b], 0, 0, 0);
            accS[b] = __builtin_amdgcn_mfma_f32_16x16x32_bf16(Al1, Bh1, accS[b], 0, 0, 0);
            accS[b] = __builtin_amdgcn_mfma_f32_16x16x32_bf16(Am1, Bl1, accS[b], 0, 0, 0);
            accS[b] = __builtin_amdgcn_mfma_f32_16x16x32_bf16(Al1, Bm1, accS[b], 0, 0, 0);
        }

        // ---- per-lane argmax over 8 code tiles (idx ascending -> first-tie) ----
        // D layout: row = q*4 + r, col(code) = b*16 + lm
        float bv[4]; int bi[4];
        #pragma unroll
        for (int r = 0; r < 4; ++r) {
            bv[r] = accB[0][r] + accS[0][r];
            bi[r] = lm;
            #pragma unroll
            for (int b = 1; b < 8; ++b) {
                const float v = accB[b][r] + accS[b][r];
                if (v > bv[r]) { bv[r] = v; bi[r] = b * 16 + lm; }
            }
        }
        // ---- butterfly across the 16 lanes of each quad ----
        #pragma unroll
        for (int mask = 1; mask <= 8; mask <<= 1) {
            #pragma unroll
            for (int r = 0; r < 4; ++r) {
                const float ov = __shfl_xor(bv[r], mask);
                const int   oi = __shfl_xor(bi[r], mask);
                if (ov > bv[r] || (ov == bv[r] && oi < bi[r])) { bv[r] = ov; bi[r] = oi; }
            }
        }
        // lane lm==0 of each quad publishes rows q*4+{0..3} to wave scratch
        if (lm == 0)
            *(int4*)&swx[w * 16 + q * 4] = make_int4(bi[0], bi[1], bi[2], bi[3]);
        // (same-wave DS ordering: compiler inserts lgkmcnt before the reads)

        // ---- coalesced one-hot write: 8 passes x 1KB ----
        float4* __restrict__ op = (float4*)(out + rw0 * SS);
        #pragma unroll
        for (int p = 0; p < 8; ++p) {
            const int row  = p * 2 + (lane >> 5);
            const int col4 = (p * 64 + lane) & 31;
            const int am = swx[w * 16 + row];
            const int s0 = col4 * 4;
            float4 v;
            v.x = (s0 + 0 == am) ? 1.f : 0.f;
            v.y = (s0 + 1 == am) ? 1.f : 0.f;
            v.z = (s0 + 2 == am) ? 1.f : 0.f;
            v.w = (s0 + 3 == am) ? 1.f : 0.f;
            op[row * (SS / 4) + col4] = v;
        }

        ra0 = na0; ra1 = na1; rb0 = nb0; rb1 = nb1;
    }

    // ---- copy c to second output (first 128 blocks x 256 thr) ----
    if (blk < 128) {
        const float4* __restrict__ src = (const float4*)c;
        float4* __restrict__ dst = (float4*)out_c;
        const int idx = blk * 256 + tid;
        dst[idx] = src[idx];
    }
}

extern "C" void kernel_launch(void* const* d_in, const int* in_sizes, int n_in,
                              void* d_out, int out_size, void* d_ws, size_t ws_size,
                              hipStream_t stream) {
    const float* x = (const float*)d_in[0];   // [B,H,L,D] fp32
    const float* c = (const float*)d_in[1];   // [H,S,D]   fp32
    float* out = (float*)d_out;               // onehot [B,H,L,S] then c [H,S,D]
    float* out_c = out + (size_t)BB * HH * LL * SS;

    const int rows = BB * HH * LL;            // 262144
    const int blocks = rows / 512;            // 512
    quantizer_kernel<<<blocks, 256, 0, stream>>>(x, c, out, out_c);
}

// Round 10
// 210.891 us; speedup vs baseline: 1.1056x; 1.1056x over previous
//
#include <hip/hip_runtime.h>
#include <hip/hip_bf16.h>
#include <math.h>

// Problem constants: B=4, H=16, L=4096, D=64, S=128
constexpr int BB = 4;
constexpr int HH = 16;
constexpr int LL = 4096;
constexpr int DD = 64;
constexpr int SS = 128;
constexpr int NT = 8;      // tiles (of 16 rows) per wave
// block = 256 thr = 4 waves; rows/block = 4*16*NT = 512; grid = 512 (2/CU resident)

// R10 = R9 with the nontemporal store fixed (must use clang ext-vector type,
// not HIP's float4 class). R9 theory unchanged:
//   1) __launch_bounds__(256,1): VGPR cap 512 (LDS 61.7KB already limits to
//      2 blocks/CU, so no occupancy loss).
//   2) Codes processed in two halves of 64: accB[4]+accS[4]=32 regs reused
//      across halves (peak demand ~150 -> fits). Ascending half order keeps
//      np.argmax first-index tie semantics.
// Numerics unchanged (R6/R7/R8-proven exact bf16x3: hi*hi in own fp32 acc,
// 7 small segments in second acc). Stride-80 B-planes: conflicts=0 (R8 ✓).

typedef __attribute__((ext_vector_type(8))) short bf16x8;
typedef __attribute__((ext_vector_type(4))) float f32x4;

__device__ __forceinline__ void split3reg(f32x4 v0, f32x4 v1,
                                          bf16x8& H8, bf16x8& M8, bf16x8& L8) {
    float v[8];
    *(f32x4*)&v[0] = v0;
    *(f32x4*)&v[4] = v1;
    short H[8], M[8], L[8];
    #pragma unroll
    for (int e = 0; e < 8; ++e) {
        const float xv = v[e];
        const unsigned u0 = __float_as_uint(xv);
        const float hf = __uint_as_float(u0 & 0xFFFF0000u);
        const float r1 = xv - hf;                       // exact
        const unsigned u1 = __float_as_uint(r1);
        const float mf = __uint_as_float(u1 & 0xFFFF0000u);
        const float r2 = r1 - mf;                       // exact, <=8 sig bits
        const unsigned u2 = __float_as_uint(r2);
        H[e] = (short)(u0 >> 16);
        M[e] = (short)(u1 >> 16);
        L[e] = (short)(u2 >> 16);                       // exact bf16
    }
    H8 = *(bf16x8*)H; M8 = *(bf16x8*)M; L8 = *(bf16x8*)L;
}

__global__ __launch_bounds__(256, 1) void quantizer_kernel(
    const float* __restrict__ x,   // [B,H,L,D]
    const float* __restrict__ c,   // [H,S,D]
    float* __restrict__ out,       // [B,H,L,S] one-hot
    float* __restrict__ out_c)     // [H,S,D] copy of c
{
    // B planes: 3 x [128 codes][80 shorts] (stride 160B: 16B-aligned b128)
    alignas(16) __shared__ short smem[3 * 128 * 80 + 128];
    short* __restrict__ sBh = smem;
    short* __restrict__ sBm = smem + 10240;
    short* __restrict__ sBl = smem + 20480;
    int*   __restrict__ swx = (int*)(smem + 30720);   // per-wave amax scratch

    const int tid = threadIdx.x;
    const int blk = blockIdx.x;
    const long long r0 = (long long)blk * 512;
    const int h = (blk >> 3) & (HH - 1);              // 512 | 4096
    const float* __restrict__ chead = c + (size_t)h * SS * DD;

    // ---- stage + split codebook: 1024 octet-tasks, 4 per thread ----
    #pragma unroll
    for (int i = 0; i < 4; ++i) {
        const int t = tid + i * 256;
        const int code = t >> 3, oct = t & 7;
        const f32x4* cp = (const f32x4*)(chead + code * DD + oct * 8);
        bf16x8 H, M, L;
        split3reg(cp[0], cp[1], H, M, L);
        *(bf16x8*)&sBh[code * 80 + oct * 8] = H;
        *(bf16x8*)&sBm[code * 80 + oct * 8] = M;
        *(bf16x8*)&sBl[code * 80 + oct * 8] = L;
    }
    __syncthreads();   // the ONLY barrier

    const int lane = tid & 63;
    const int w = tid >> 6;        // wave id 0..3
    const int lm = lane & 15;      // m-row / n-code within 16x16 tile
    const int q  = lane >> 4;      // k-group (k = q*8+j) / D-row quad

    // per-lane x loads for A fragments: row rw0+lm, k halves [q*8, q*8+8)
    auto loadraw = [&](long long rw0, f32x4& a0, f32x4& a1, f32x4& b0, f32x4& b1) {
        const float* p = x + (rw0 + lm) * (long long)DD;
        a0 = *(const f32x4*)(p + q * 8);
        a1 = *(const f32x4*)(p + q * 8 + 4);
        b0 = *(const f32x4*)(p + 32 + q * 8);
        b1 = *(const f32x4*)(p + 32 + q * 8 + 4);
    };

    f32x4 ra0, ra1, rb0, rb1;                  // current tile raw x
    f32x4 na0 = {}, na1 = {}, nb0 = {}, nb1 = {};
    loadraw(r0 + w * 16, ra0, ra1, rb0, rb1);

    #pragma unroll 1
    for (int t = 0; t < NT; ++t) {
        const long long rw0 = r0 + t * 64 + w * 16;
        if (t + 1 < NT) loadraw(rw0 + 64, na0, na1, nb0, nb1);   // prefetch

        bf16x8 Ah0, Am0, Al0, Ah1, Am1, Al1;
        split3reg(ra0, ra1, Ah0, Am0, Al0);
        split3reg(rb0, rb1, Ah1, Am1, Al1);

        float bv[4]; int bi[4];

        // ---- two half-passes over codes: 4 tiles each, acc regs reused ----
        #pragma unroll
        for (int half = 0; half < 2; ++half) {
            f32x4 accB[4] = {};   // hi*hi
            f32x4 accS[4] = {};   // 7 small segments
            #pragma unroll
            for (int bb = 0; bb < 4; ++bb) {
                const int n = (half * 4 + bb) * 16 + lm;
                const bf16x8 Bh0 = *(const bf16x8*)&sBh[n * 80 + q * 8];
                const bf16x8 Bm0 = *(const bf16x8*)&sBm[n * 80 + q * 8];
                const bf16x8 Bl0 = *(const bf16x8*)&sBl[n * 80 + q * 8];
                const bf16x8 Bh1 = *(const bf16x8*)&sBh[n * 80 + 32 + q * 8];
                const bf16x8 Bm1 = *(const bf16x8*)&sBm[n * 80 + 32 + q * 8];
                const bf16x8 Bl1 = *(const bf16x8*)&sBl[n * 80 + 32 + q * 8];
                accB[bb] = __builtin_amdgcn_mfma_f32_16x16x32_bf16(Ah0, Bh0, accB[bb], 0, 0, 0);
                accB[bb] = __builtin_amdgcn_mfma_f32_16x16x32_bf16(Ah1, Bh1, accB[bb], 0, 0, 0);
                accS[bb] = __builtin_amdgcn_mfma_f32_16x16x32_bf16(Ah0, Bm0, accS[bb], 0, 0, 0);
                accS[bb] = __builtin_amdgcn_mfma_f32_16x16x32_bf16(Am0, Bh0, accS[bb], 0, 0, 0);
                accS[bb] = __builtin_amdgcn_mfma_f32_16x16x32_bf16(Am0, Bm0, accS[bb], 0, 0, 0);
                accS[bb] = __builtin_amdgcn_mfma_f32_16x16x32_bf16(Ah0, Bl0, accS[bb], 0, 0, 0);
                accS[bb] = __builtin_amdgcn_mfma_f32_16x16x32_bf16(Al0, Bh0, accS[bb], 0, 0, 0);
                accS[bb] = __builtin_amdgcn_mfma_f32_16x16x32_bf16(Am0, Bl0, accS[bb], 0, 0, 0);
                accS[bb] = __builtin_amdgcn_mfma_f32_16x16x32_bf16(Al0, Bm0, accS[bb], 0, 0, 0);
                accS[bb] = __builtin_amdgcn_mfma_f32_16x16x32_bf16(Ah1, Bm1, accS[bb], 0, 0, 0);
                accS[bb] = __builtin_amdgcn_mfma_f32_16x16x32_bf16(Am1, Bh1, accS[bb], 0, 0, 0);
                accS[bb] = __builtin_amdgcn_mfma_f32_16x16x32_bf16(Am1, Bm1, accS[bb], 0, 0, 0);
                accS[bb] = __builtin_amdgcn_mfma_f32_16x16x32_bf16(Ah1, Bl1, accS[bb], 0, 0, 0);
                accS[bb] = __builtin_amdgcn_mfma_f32_16x16x32_bf16(Al1, Bh1, accS[bb], 0, 0, 0);
                accS[bb] = __builtin_amdgcn_mfma_f32_16x16x32_bf16(Am1, Bl1, accS[bb], 0, 0, 0);
                accS[bb] = __builtin_amdgcn_mfma_f32_16x16x32_bf16(Al1, Bm1, accS[bb], 0, 0, 0);
            }
            // per-lane argmax over this half's 4 tiles (ascending index)
            // D layout: row = q*4 + r, col(code) = (half*4+bb)*16 + lm
            #pragma unroll
            for (int r = 0; r < 4; ++r) {
                if (half == 0) {
                    bv[r] = accB[0][r] + accS[0][r];
                    bi[r] = lm;
                }
                #pragma unroll
                for (int bb = (half == 0 ? 1 : 0); bb < 4; ++bb) {
                    const float v = accB[bb][r] + accS[bb][r];
                    const int ci = (half * 4 + bb) * 16 + lm;
                    if (v > bv[r]) { bv[r] = v; bi[r] = ci; }
                }
            }
        }

        // ---- butterfly across the 16 lanes of each quad ----
        #pragma unroll
        for (int mask = 1; mask <= 8; mask <<= 1) {
            #pragma unroll
            for (int r = 0; r < 4; ++r) {
                const float ov = __shfl_xor(bv[r], mask);
                const int   oi = __shfl_xor(bi[r], mask);
                if (ov > bv[r] || (ov == bv[r] && oi < bi[r])) { bv[r] = ov; bi[r] = oi; }
            }
        }
        // lane lm==0 of each quad publishes rows q*4+{0..3} to wave scratch
        if (lm == 0)
            *(int4*)&swx[w * 16 + q * 4] = make_int4(bi[0], bi[1], bi[2], bi[3]);

        // ---- coalesced one-hot write: 8 passes x 1KB, nontemporal ----
        f32x4* __restrict__ op = (f32x4*)(out + rw0 * SS);
        #pragma unroll
        for (int p = 0; p < 8; ++p) {
            const int row  = p * 2 + (lane >> 5);
            const int col4 = (p * 64 + lane) & 31;
            const int am = swx[w * 16 + row];
            const int s0 = col4 * 4;
            f32x4 v;
            v.x = (s0 + 0 == am) ? 1.f : 0.f;
            v.y = (s0 + 1 == am) ? 1.f : 0.f;
            v.z = (s0 + 2 == am) ? 1.f : 0.f;
            v.w = (s0 + 3 == am) ? 1.f : 0.f;
            __builtin_nontemporal_store(v, &op[row * (SS / 4) + col4]);
        }

        ra0 = na0; ra1 = na1; rb0 = nb0; rb1 = nb1;
    }

    // ---- copy c to second output (first 128 blocks x 256 thr) ----
    if (blk < 128) {
        const f32x4* __restrict__ src = (const f32x4*)c;
        f32x4* __restrict__ dst = (f32x4*)out_c;
        const int idx = blk * 256 + tid;
        dst[idx] = src[idx];
    }
}

extern "C" void kernel_launch(void* const* d_in, const int* in_sizes, int n_in,
                              void* d_out, int out_size, void* d_ws, size_t ws_size,
                              hipStream_t stream) {
    const float* x = (const float*)d_in[0];   // [B,H,L,D] fp32
    const float* c = (const float*)d_in[1];   // [H,S,D]   fp32
    float* out = (float*)d_out;               // onehot [B,H,L,S] then c [H,S,D]
    float* out_c = out + (size_t)BB * HH * LL * SS;

    const int rows = BB * HH * LL;            // 262144
    const int blocks = rows / 512;            // 512
    quantizer_kernel<<<blocks, 256, 0, stream>>>(x, c, out, out_c);
}